// Round 18
// baseline (138.522 us; speedup 1.0000x reference)
//
#include <hip/hip_runtime.h>
#include <math.h>

typedef int i32x4 __attribute__((ext_vector_type(4)));
typedef int i32x16 __attribute__((ext_vector_type(16)));

#define CC 248
#define MM 65536
#define NN 1024

__device__ __forceinline__ float fexp2(float x) { return __builtin_amdgcn_exp2f(x); }

// ws: B_tiled [2][32 ntiles][pl 2][kg 16][col 32][16] (i8 hi/lo) = 1,048,576 B
//     partials [2][1024][512 mc] float4                          = 16,777,216 B

// ---------------- convA: keypoint descriptors -> i8 hi/lo planes, 32-col tiles ----------------
__global__ __launch_bounds__(256)
void convA_kernel(const float* __restrict__ kdesc, char* __restrict__ Bg) {
    __shared__ char bt[2][16][32][16];        // 16 KB
    __shared__ float scr[8][32];
    const int bid = blockIdx.x;               // 0..63
    const int b   = bid >> 5;
    const int nt  = bid & 31;
    const int n0  = nt * 32;
    const int tid = threadIdx.x;
    const int col = tid & 31;
    const int q   = tid >> 5;                 // 0..7 -> channels q*31..q*31+30

    const float* kp = kdesc + (size_t)(2 * b + 1) * CC * NN + n0 + col;
    float ss = 0.f;
    for (int i = 0; i < 31; ++i) {
        int c = q * 31 + i;
        float v = kp[(size_t)c * NN];
        ss += v * v;
    }
    scr[q][col] = ss;
    __syncthreads();
    float tot = 0.f;
#pragma unroll
    for (int k = 0; k < 8; ++k) tot += scr[k][col];
    float inv = 32768.0f / fmaxf(sqrtf(tot), 1e-12f);
    if (tid < 64) {                            // zero k-pad c=248..255
        int pl = tid >> 5, c2 = tid & 31;
        *(long*)&bt[pl][15][c2][8] = 0L;
    }
    __syncthreads();
    for (int i = 0; i < 31; ++i) {
        int c = q * 31 + i;
        float qq = fminf(fmaxf(rintf(kp[(size_t)c * NN] * inv), -32768.f), 32639.f);
        int af = (int)qq;
        int a1 = (af + 128) >> 8;
        int a0 = af - (a1 << 8);
        bt[0][c >> 4][col][c & 15] = (char)a1;
        bt[1][c >> 4][col][c & 15] = (char)a0;
    }
    __syncthreads();
    char* outb = Bg + (size_t)(b * 32 + nt) * 16384;
    const char* src = &bt[0][0][0][0];
#pragma unroll
    for (int it = 0; it < 4; ++it) {
        int id = tid + it * 256;              // 0..1023 16B chunks
        *(i32x4*)&outb[(size_t)id * 16] = *(const i32x4*)&src[(size_t)id * 16];
    }
}

// ---------------- fused quant + i8 MFMA GEMM, quant pipelined under the gemm ----------------
// Block: 256 thr (4 waves), 2 panels of 128 pixels x ALL 1024 keypoints. Grid 512 (2/CU).
// LDS: at[pl 2][kg 16][row 128][16] = 64 KB single buffer.
// Quant split: passA = HBM read + sumsq (panel p+1's passA interleaved into panel p's gemm,
//   one chunk per nc iteration); passB = L2/L3 re-read + quantize + LDS write (short, serial).
// Sumsq finalized via __shfl_xor(ss,1): thread (row=tid>>1, half=tid&1) pairs. 2 barriers/panel.
__global__ __launch_bounds__(256, 2)
void fused_kernel(const float* __restrict__ dense, const char* __restrict__ Bg,
                  float* __restrict__ partials) {
    extern __shared__ char lds[];

    const int bid   = blockIdx.x;             // 0..511
    const int fb    = bid >> 8;               // frame 2*fb
    const int local = bid & 255;              // panels local*2 + {0,1}

    const int tid  = threadIdx.x;
    const int row  = tid >> 1;                // 0..127
    const int half = tid & 1;                 // channel half (124 each)

    const int lane = tid & 63;
    const int w    = tid >> 6;                // 0..3
    const int lrow = lane & 31;
    const int lhi  = lane >> 5;

    const float* dbase = dense + (size_t)(2 * fb) * CC * MM + (size_t)(half * 124) * MM + row;
    const char*  bbase = Bg + (size_t)(fb * 32) * 16384;

    // score*log2(e) = (65536*H + 256*X) * 100*log2(e) / 2^30 ; fixed base 145 > max
    const float S2 = 100.0f * 1.4426950408889634f / 1073741824.0f;
    const float cH = 65536.0f * S2;
    const float cX = 256.0f * S2;
    const float BASE = 145.0f;

    // pass A chunk: stream 31 channels of panel p, accumulate sumsq (values discarded)
    auto PASSA_CHUNK = [&](int p, int chunk, float& ss) {
        const float* dp = dbase + (local * 2 + p) * 128 + (size_t)(chunk * 31) * MM;
#pragma unroll
        for (int i = 0; i < 31; ++i) {
            float x = dp[(size_t)i * MM];
            ss = fmaf(x, x, ss);
        }
    };

    // pass B: re-read (L2/L3-hot) + quantize + LDS write; also zero k-pad
    auto PASSB = [&](int p, float inv) {
        const float* dp = dbase + (local * 2 + p) * 128;
        *(long*)&lds[half * 32768 + 15 * 2048 + row * 16 + 8] = 0L;
#pragma unroll
        for (int j = 0; j < 31; ++j) {
            unsigned w1 = 0, w0 = 0;
#pragma unroll
            for (int t = 0; t < 4; ++t) {
                float x = dp[(size_t)(j * 4 + t) * MM];
                float qv = fminf(fmaxf(rintf(x * inv), -32768.f), 32639.f);
                int af = (int)qv;
                int a1 = (af + 128) >> 8;
                int a0 = af - (a1 << 8);
                w1 |= (unsigned)(a1 & 255) << (8 * t);
                w0 |= (unsigned)(a0 & 255) << (8 * t);
            }
            int c0 = half * 124 + j * 4;
            int kg = c0 >> 4, dw = (c0 >> 2) & 3;
            *(unsigned*)&lds[kg * 2048 + row * 16 + dw * 4] = w1;
            *(unsigned*)&lds[32768 + kg * 2048 + row * 16 + dw * 4] = w0;
        }
    };

    // prologue: panel 0 pass A (unavoidable startup HBM burst)
    float ssn = 0.f;
#pragma unroll
    for (int c = 0; c < 4; ++c) PASSA_CHUNK(0, c, ssn);
    float ss1 = 0.f;

#pragma unroll
    for (int p = 0; p < 2; ++p) {
        float tot = ssn + __shfl_xor(ssn, 1, 64);
        float inv = 32768.0f / fmaxf(sqrtf(tot), 1e-12f);
        PASSB(p, inv);
        __syncthreads();                      // at[] complete

        const int pp0 = (local * 2 + p) * 128;

        for (int nc = 0; nc < 4; ++nc) {
            if (p == 0) PASSA_CHUNK(1, nc, ss1);   // panel-1 HBM rides under gemm

            // bc: both planes, full K, 2 n-tiles (64 n) -> 128 regs, from L2
            i32x4 bc[8][2][2];                 // [kk][pl][bp]
#pragma unroll
            for (int kk = 0; kk < 8; ++kk)
#pragma unroll
                for (int pl = 0; pl < 2; ++pl)
#pragma unroll
                    for (int bp = 0; bp < 2; ++bp)
                        bc[kk][pl][bp] = *(const i32x4*)(bbase
                            + (size_t)(w * 8 + nc * 2 + bp) * 16384 + pl * 8192
                            + (kk * 2 + lhi) * 512 + lrow * 16);

            float rz[2] = {0.f, 0.f}, rsu[2] = {0.f, 0.f}, rsv[2] = {0.f, 0.f};

#pragma unroll
            for (int mt = 0; mt < 4; ++mt) {
                i32x16 accH[2], accX[2];
#pragma unroll
                for (int bp = 0; bp < 2; ++bp) { accH[bp] = (i32x16)(0); accX[bp] = (i32x16)(0); }

#pragma unroll
                for (int kk = 0; kk < 8; ++kk) {
                    i32x4 a1 = *(const i32x4*)&lds[(kk * 2 + lhi) * 2048 + (mt * 32 + lrow) * 16];
                    i32x4 a0 = *(const i32x4*)&lds[32768 + (kk * 2 + lhi) * 2048 + (mt * 32 + lrow) * 16];
                    __builtin_amdgcn_s_setprio(1);
#pragma unroll
                    for (int bp = 0; bp < 2; ++bp) {
                        accH[bp] = __builtin_amdgcn_mfma_i32_32x32x32_i8(a1, bc[kk][0][bp], accH[bp], 0, 0, 0);
                        accX[bp] = __builtin_amdgcn_mfma_i32_32x32x32_i8(a1, bc[kk][1][bp], accX[bp], 0, 0, 0);
                        accX[bp] = __builtin_amdgcn_mfma_i32_32x32x32_i8(a0, bc[kk][0][bp], accX[bp], 0, 0, 0);
                    }
                    __builtin_amdgcn_s_setprio(0);
                }

                // fixed-base EPI (no max, no rescale)
                const int mbase = pp0 + mt * 32;
                const float ub = (float)((mbase & 255) + 4 * lhi);
                const float vcoord = (float)(mbase >> 8);
#pragma unroll
                for (int bp = 0; bp < 2; ++bp) {
                    float tz = 0.f, tsur = 0.f;
#pragma unroll
                    for (int r = 0; r < 16; ++r) {
                        float e = fexp2(fmaf((float)accH[bp][r], cH,
                                        fmaf((float)accX[bp][r], cX, -BASE)));
                        tz += e;
                        tsur = fmaf(e, (float)((r & 3) + 8 * (r >> 2)), tsur);
                    }
                    rz[bp] += tz;
                    rsu[bp] += fmaf(ub, tz, tsur);
                    rsv[bp] = fmaf(vcoord, tz, rsv[bp]);
                }
            }

            // merge lane <-> lane+32 (plain sums), write partials (Z,Su,Sv)
#pragma unroll
            for (int bp = 0; bp < 2; ++bp) {
                rz[bp]  += __shfl_xor(rz[bp],  32, 64);
                rsu[bp] += __shfl_xor(rsu[bp], 32, 64);
                rsv[bp] += __shfl_xor(rsv[bp], 32, 64);
            }
            if (lane < 32) {
#pragma unroll
                for (int bp = 0; bp < 2; ++bp) {
                    int n = w * 256 + nc * 64 + bp * 32 + lrow;
                    size_t idxp = ((size_t)(fb * NN + n)) * 512 + (local * 2 + p);
                    ((float4*)partials)[idxp] = make_float4(rz[bp], rsu[bp], rsv[bp], 0.f);
                }
            }
        }

        if (p == 0) {
            __syncthreads();                   // all waves done reading buf before overwrite
            ssn = ss1;
        }
    }
}

// ---------------- combine: plain sum of 512 partials per (b,n) row ----------------
__global__ __launch_bounds__(256)
void combine_kernel(const float* __restrict__ partials,
                    const float* __restrict__ kscores,
                    const float* __restrict__ times,
                    float* __restrict__ out) {
    const int wg   = blockIdx.x * 4 + (threadIdx.x >> 6);  // 0..2047 = (b, n)
    const int lane = threadIdx.x & 63;
    const int b = wg >> 10, n = wg & 1023;
    const float4* pp = (const float4*)partials + (size_t)wg * 512;

    float z = 0.f, su = 0.f, sv = 0.f;
#pragma unroll
    for (int k = 0; k < 8; ++k) {
        float4 p = pp[k * 64 + lane];
        z += p.x; su += p.y; sv += p.z;
    }
#pragma unroll
    for (int mask = 32; mask >= 1; mask >>= 1) {
        z  += __shfl_xor(z,  mask, 64);
        su += __shfl_xor(su, mask, 64);
        sv += __shfl_xor(sv, mask, 64);
    }

    if (lane == 0) {
        float u = su / z, v = sv / z;
        out[(size_t)wg * 2 + 0] = u;
        out[(size_t)wg * 2 + 1] = v;
        out[4096 + wg] = kscores[(size_t)(2 * b + 1) * NN + n];
        if (wg == 0) { out[6144] = 1.0f; out[6145] = 3.0f; }

        const float* timg = times + (size_t)(2 * b) * MM;
        float u0 = fminf(fmaxf(floorf(u), 0.f), 255.f);
        float v0 = fminf(fmaxf(floorf(v), 0.f), 255.f);
        float u1 = fminf(u0 + 1.f, 255.f);
        float v1 = fminf(v0 + 1.f, 255.f);
        float au = u - u0, av = v - v0;
        int u0i = (int)u0, u1i = (int)u1, v0i = (int)v0, v1i = (int)v1;
        float t00 = timg[v0i * 256 + u0i], t01 = timg[v0i * 256 + u1i];
        float t10 = timg[v1i * 256 + u0i], t11 = timg[v1i * 256 + u1i];
        float t = t00 * (1.f - au) * (1.f - av) + t01 * au * (1.f - av)
                + t10 * (1.f - au) * av + t11 * au * av;
        out[6146 + wg] = t;
    }
}

extern "C" void kernel_launch(void* const* d_in, const int* in_sizes, int n_in,
                              void* d_out, int out_size, void* d_ws, size_t ws_size,
                              hipStream_t stream) {
    const float* kscores = (const float*)d_in[0];
    const float* kdesc   = (const float*)d_in[1];
    const float* dense   = (const float*)d_in[2];
    const float* times   = (const float*)d_in[3];
    float* out = (float*)d_out;

    char* Bg = (char*)d_ws;                                   //  1,048,576 B
    float* partials = (float*)(Bg + (size_t)2 * 32 * 16384);  // 16,777,216 B

    hipFuncSetAttribute((const void*)fused_kernel,
                        hipFuncAttributeMaxDynamicSharedMemorySize, 65536);

    hipLaunchKernelGGL(convA_kernel,   dim3(64),   dim3(256), 0, stream, kdesc, Bg);
    hipLaunchKernelGGL(fused_kernel,   dim3(512),  dim3(256), 65536, stream, dense, Bg, partials);
    hipLaunchKernelGGL(combine_kernel, dim3(512),  dim3(256), 0, stream, partials, kscores, times, out);
}